// Round 16
// baseline (257.691 us; speedup 1.0000x reference)
//
#include <hip/hip_runtime.h>
#include <hip/hip_bf16.h>

typedef short bf16x8 __attribute__((ext_vector_type(8)));
typedef short bf16x4 __attribute__((ext_vector_type(4)));
typedef float f32x4  __attribute__((ext_vector_type(4)));

#define LDP 72   // padded LDS row (bf16 elems) for attn tiles

__device__ __forceinline__ float bits2f(short u) {
  return __uint_as_float(((unsigned int)(unsigned short)u) << 16);
}
__device__ __forceinline__ short f2bits(float f) {
  __hip_bfloat16 h = __float2bfloat16(f);
  return *reinterpret_cast<short*>(&h);
}
// async global->LDS, 16B per lane; LDS dest = wave-uniform base + lane*16
__device__ __forceinline__ void gld16(const short* g, short* l) {
  __builtin_amdgcn_global_load_lds(
      (const __attribute__((address_space(1))) void*)g,
      (__attribute__((address_space(3))) void*)l, 16, 0, 0);
}

// ---------------- fp32 -> bf16 casts (separate kernels, r7-verified) ----------------
__global__ __launch_bounds__(256)
void cvt_x_kernel(const float* __restrict__ src, short* __restrict__ dst, long n) {
  long i = ((long)blockIdx.x * 256 + threadIdx.x) * 4;
  if (i + 3 < n) {
    float4 v = *(const float4*)(src + i);
    bf16x4 o;
    o[0] = f2bits(v.x); o[1] = f2bits(v.y); o[2] = f2bits(v.z); o[3] = f2bits(v.w);
    *(bf16x4*)(dst + i) = o;
  }
}

__global__ __launch_bounds__(256)
void cvt_w_kernel(const float* __restrict__ w0, const float* __restrict__ w1,
                  const float* __restrict__ w2, const float* __restrict__ w3,
                  short* __restrict__ dst) {
  long i = ((long)blockIdx.x * 256 + threadIdx.x) * 4;
  int sel = (int)(i >> 20);
  const float* s = (sel == 0) ? w0 : (sel == 1) ? w1 : (sel == 2) ? w2 : w3;
  long off = i & ((1L << 20) - 1);
  float4 v = *(const float4*)(s + off);
  bf16x4 o;
  o[0] = f2bits(v.x); o[1] = f2bits(v.y); o[2] = f2bits(v.z); o[3] = f2bits(v.w);
  *(bf16x4*)(dst + i) = o;
}

// ---------------- GEMM (NT): Out = A[M][K] @ Bm[N][K]^T ----------------
// r6-verified: m97 2-phase, BK=64, XOR-swizzled LDS (0 bank conflicts), ~111us QKV.
// MODE 2: fp32 row-major [M][N] -> OutF
// MODE 3: fused QKV epilogue (N=3072): n<1024 -> Oq; n<2048 -> Ok; else V-transpose -> Ov
template<int MODE>
__global__ __launch_bounds__(256)
void gemm_nt(const short* __restrict__ A, const short* __restrict__ Bm,
             float* __restrict__ OutF, short* __restrict__ Oq,
             short* __restrict__ Ok, short* __restrict__ Ov,
             int M, int K, int N, int T, int TPAD) {
  __shared__ short As[128 * 64];
  __shared__ short Bs[128 * 64];
  const int tid = threadIdx.x;
  const int w = tid >> 6, l = tid & 63;
  const int wr = w >> 1, wc = w & 1;
  const int lg = l >> 4, lo = l & 15;
  const long row0 = (long)blockIdx.x * 128;
  const long col0 = (long)blockIdx.y * 128;

  const short* pa[4]; const short* pb[4]; short* la[4]; short* lb[4];
#pragma unroll
  for (int j = 0; j < 4; ++j) {
    const int ch = w * 4 + j;
    const int off = ch * 1024 + l * 16;             // byte offset in tile (lane's dest)
    const int row = off >> 7;                       // 128 B per row
    const int lc  = (off & 127) ^ ((row & 7) << 4); // inverse-swizzled source col (bytes)
    long ga = row0 + row; if (ga > M - 1) ga = M - 1;
    pa[j] = &A[ga * K + (lc >> 1)];
    pb[j] = &Bm[(col0 + row) * K + (lc >> 1)];
    la[j] = &As[ch * 512];                          // wave-uniform LDS base
    lb[j] = &Bs[ch * 512];
  }

  f32x4 acc[4][4] = {};

  for (int kt = 0; kt < K; kt += 64) {
    __syncthreads();
#pragma unroll
    for (int j = 0; j < 4; ++j) {
      gld16(pa[j] + kt, la[j]);
      gld16(pb[j] + kt, lb[j]);
    }
    __syncthreads();                       // compiler drains vmcnt before s_barrier
    bf16x8 af[4][2], bfr[4][2];
#pragma unroll
    for (int mi = 0; mi < 4; ++mi)
#pragma unroll
      for (int ks = 0; ks < 2; ++ks) {
        int pe = (ks * 32 + lg * 8) ^ ((lo & 7) << 3);   // swizzled read (elems)
        af[mi][ks] = *(const bf16x8*)(&As[(wr * 64 + mi * 16 + lo) * 64 + pe]);
      }
#pragma unroll
    for (int ni = 0; ni < 4; ++ni)
#pragma unroll
      for (int ks = 0; ks < 2; ++ks) {
        int pe = (ks * 32 + lg * 8) ^ ((lo & 7) << 3);
        bfr[ni][ks] = *(const bf16x8*)(&Bs[(wc * 64 + ni * 16 + lo) * 64 + pe]);
      }
#pragma unroll
    for (int mi = 0; mi < 4; ++mi)
#pragma unroll
      for (int ni = 0; ni < 4; ++ni)
#pragma unroll
        for (int ks = 0; ks < 2; ++ks)
          acc[mi][ni] = __builtin_amdgcn_mfma_f32_16x16x32_bf16(af[mi][ks], bfr[ni][ks], acc[mi][ni], 0, 0, 0);
  }

#pragma unroll
  for (int mi = 0; mi < 4; ++mi) {
#pragma unroll
    for (int r = 0; r < 4; ++r) {
      long m = row0 + wr * 64 + mi * 16 + lg * 4 + r;
      if (m >= M) continue;
#pragma unroll
      for (int ni = 0; ni < 4; ++ni) {
        long n = col0 + wc * 64 + ni * 16 + lo;
        float v = acc[mi][ni][r];
        if constexpr (MODE == 2) {
          OutF[m * (long)N + n] = v;
        } else {
          if (n < 1024) {
            Oq[m * 1024 + n] = f2bits(v);
          } else if (n < 2048) {
            Ok[m * 1024 + (n - 1024)] = f2bits(v);
          } else {
            long b = m / T, t = m - b * T;
            long nn = n - 2048, h = nn >> 6, dd = nn & 63;
            Ov[((b * 16 + h) * 64 + dd) * TPAD + t] = f2bits(v);
          }
        }
      }
    }
  }
}

// ---------------- LayerNorm(C=1024) + axial RoPE, write (B,H,T,D) bf16 ----------------
__global__ __launch_bounds__(256)
void ln_rope_kernel(const short* __restrict__ qpre, const short* __restrict__ kpre,
                    const float* __restrict__ qg, const float* __restrict__ qb2,
                    const float* __restrict__ kg, const float* __restrict__ kb2,
                    short* __restrict__ qa, short* __restrict__ ka, int T) {
  const int row = blockIdx.x;
  const short* in; const float *g, *be; short* out;
  if (blockIdx.y == 0) { in = qpre; g = qg; be = qb2; out = qa; }
  else                 { in = kpre; g = kg; be = kb2; out = ka; }
  const int tid = threadIdx.x;
  const int c0 = tid * 4;

  bf16x4 xv = *(const bf16x4*)(&in[(long)row * 1024 + c0]);
  float xf[4];
  float s = 0.f, sq = 0.f;
#pragma unroll
  for (int i = 0; i < 4; ++i) { xf[i] = bits2f(xv[i]); s += xf[i]; sq += xf[i] * xf[i]; }
#pragma unroll
  for (int o = 1; o < 64; o <<= 1) { s += __shfl_xor(s, o); sq += __shfl_xor(sq, o); }
  __shared__ float red[8];
  const int w = tid >> 6, l = tid & 63;
  if (l == 0) { red[w] = s; red[4 + w] = sq; }
  __syncthreads();
  s  = red[0] + red[1] + red[2] + red[3];
  sq = red[4] + red[5] + red[6] + red[7];
  const float mean = s * (1.0f / 1024.0f);
  const float var  = sq * (1.0f / 1024.0f) - mean * mean;
  const float rstd = rsqrtf(var + 1e-5f);

  float4 gv = *(const float4*)(&g[c0]);
  float4 bv = *(const float4*)(&be[c0]);
  float z[4];
  z[0] = (xf[0] - mean) * rstd * gv.x + bv.x;
  z[1] = (xf[1] - mean) * rstd * gv.y + bv.y;
  z[2] = (xf[2] - mean) * rstd * gv.z + bv.z;
  z[3] = (xf[3] - mean) * rstd * gv.w + bv.w;

  const int t = row % T;
  const int p = t - 6;                 // prefix = POSE + YAW = 6
  if (p >= 0) {
    const float tx = (float)(p % 18);  // END_X = 18
    const float ty = (float)(p / 18);
    const int jbase = (c0 & 63) >> 1;  // pair index 0..31
#pragma unroll
    for (int q2 = 0; q2 < 2; ++q2) {
      const int jj = jbase + q2;
      const int i  = jj & 15;
      const float freq = exp2f(-(float)i * 0.6228615177913804f); // log2(1000)/16
      const float ang  = ((jj < 16) ? tx : ty) * freq;
      float sv, cv;
      sincosf(ang, &sv, &cv);
      const float xe = z[q2 * 2], xo = z[q2 * 2 + 1];
      z[q2 * 2]     = xe * cv - xo * sv;
      z[q2 * 2 + 1] = xe * sv + xo * cv;
    }
  }
  const long b = row / T;
  const int h = c0 >> 6, d = c0 & 63;
  bf16x4 ov;
#pragma unroll
  for (int i = 0; i < 4; ++i) ov[i] = f2bits(z[i]);
  *(bf16x4*)(&out[(((b * 16 + h) * T) + t) * 64 + d]) = ov;
}

// ---------------- causal flash attention: QBLK=128, 8 waves (one 16-row strip each) --------
// Same per-wave structure as the r15 session-best (LDS-staged K/V, reg-prefetch,
// 2 barriers/tile, defer-max, mask hoist) but 128 q-rows per block -> K/V tile
// visits drop from sum(qb+1)=55 to sum(2qb+2)=30 per (b,h): ~0.55x K/V re-read
// traffic (the measured attn bottleneck). Each of 8 waves owns ONE strip (not r5's
// failed 2-serial-strips). Mask: tiles kt < 2*qb provably unmasked (keys <=
// qb*128-1 < qrow, and <= 511 < 582); kt >= 2*qb get full mask (covers causality
// AND key >= T). Waves fully below the tile skip compute (wave-uniform branch;
// barriers still honored). Unconditional loads: overruns land in mapped ws buffers.
__global__ __launch_bounds__(512)
void attn_kernel(const short* __restrict__ Q, const short* __restrict__ Kk,
                 const short* __restrict__ Vt, short* __restrict__ Y,
                 int T, int TPAD) {
  __shared__ short QP[128 * LDP];         // Qs (prologue) aliased with 8 wave-private Ps
  __shared__ short Ks[64 * LDP];
  __shared__ short Vs[64 * LDP];          // Vs[d][key]
  const int tid = threadIdx.x;
  const int w = tid >> 6, l = tid & 63, lg = l >> 4, lo = l & 15;
  const int qb = gridDim.x - 1 - blockIdx.x;   // heavy causal blocks first
  const int bh = blockIdx.y;
  const int b = bh >> 4, h = bh & 15;
  const long qbase = (long)bh * T * 64;
  short* Qs = QP;
  short* Ps = QP + w * 16 * LDP;          // wave-private P tile (8 x 16 rows = 128 = QP)

  const int r0 = tid >> 3, c0s = (tid & 7) * 8;   // 512 threads: one 16B chunk each

  // Q stage: 128 rows x 64 cols = 1024 chunks, 2 per thread
#pragma unroll
  for (int j = 0; j < 2; ++j) {
    int ch = tid + j * 512;
    int r = ch >> 3, c = (ch & 7) * 8;
    int t = qb * 128 + r; if (t > T - 1) t = T - 1;
    *(bf16x8*)(&Qs[r * LDP + c]) = *(const bf16x8*)(&Q[qbase + (long)t * 64 + c]);
  }
  __syncthreads();
  bf16x8 qf[2];
  qf[0] = *(const bf16x8*)(&Qs[(w * 16 + lo) * LDP + lg * 8]);
  qf[1] = *(const bf16x8*)(&Qs[(w * 16 + lo) * LDP + 32 + lg * 8]);

  float mrow[4], lsum[4];
  f32x4 oacc[4] = {};
#pragma unroll
  for (int r = 0; r < 4; ++r) { mrow[r] = -3e38f; lsum[r] = 0.f; }
  const float SCL = 0.125f * 1.44269504f;
  const int nkt = 2 * qb + 2;
  const int myTop = qb * 128 + w * 16 + 15;    // last q-row this wave owns

  bf16x8 kreg, vreg;
  const long vbase = (long)bh * 64;
  auto LOADKV = [&](int kt) {
    kreg = *(const bf16x8*)(&Kk[qbase + (long)(kt * 64 + r0) * 64 + c0s]);
    vreg = *(const bf16x8*)(&Vt[(vbase + r0) * TPAD + (long)kt * 64 + c0s]);
  };
  LOADKV(0);

  for (int kt = 0; kt < nkt; ++kt) {
    __syncthreads();                     // prev PV done reading Ks/Vs
    *(bf16x8*)(&Ks[r0 * LDP + c0s]) = kreg;
    *(bf16x8*)(&Vs[r0 * LDP + c0s]) = vreg;
    __syncthreads();                     // tile staged
    if (kt + 1 < nkt) LOADKV(kt + 1);    // reg prefetch hides HBM under softmax+MFMA

    if (kt * 64 > myTop) continue;       // wave fully masked for this tile (uniform)

    f32x4 sf[4] = {};
#pragma unroll
    for (int ni = 0; ni < 4; ++ni)
#pragma unroll
      for (int kk = 0; kk < 2; ++kk) {
        bf16x8 kfr = *(const bf16x8*)(&Ks[(ni * 16 + lo) * LDP + kk * 32 + lg * 8]);
        sf[ni] = __builtin_amdgcn_mfma_f32_16x16x32_bf16(qf[kk], kfr, sf[ni], 0, 0, 0);
      }

    float pm[4][4], tmax[4];
#pragma unroll
    for (int r = 0; r < 4; ++r) tmax[r] = -3e38f;
    if (kt >= 2 * qb) {                   // diagonal region: causal + T mask
#pragma unroll
      for (int ni = 0; ni < 4; ++ni)
#pragma unroll
        for (int r = 0; r < 4; ++r) {
          int key  = kt * 64 + ni * 16 + lo;
          int qrow = qb * 128 + w * 16 + lg * 4 + r;
          float sv = sf[ni][r] * SCL;
          if (key > qrow || key >= T) sv = -3e38f;
          pm[ni][r] = sv;
          tmax[r] = fmaxf(tmax[r], sv);
        }
    } else {                              // kt < 2*qb: provably unmasked
#pragma unroll
      for (int ni = 0; ni < 4; ++ni)
#pragma unroll
        for (int r = 0; r < 4; ++r) {
          float sv = sf[ni][r] * SCL;
          pm[ni][r] = sv;
          tmax[r] = fmaxf(tmax[r], sv);
        }
    }
#pragma unroll
    for (int r = 0; r < 4; ++r)
#pragma unroll
      for (int o = 1; o < 16; o <<= 1) tmax[r] = fmaxf(tmax[r], __shfl_xor(tmax[r], o));

    // T13 defer-max at THR=0 (exact): skip the rescale pass when no row max grew
    bool need = !__all(tmax[0] <= mrow[0] && tmax[1] <= mrow[1] &&
                       tmax[2] <= mrow[2] && tmax[3] <= mrow[3]);
    if (need) {
#pragma unroll
      for (int r = 0; r < 4; ++r) {
        float mn = fmaxf(mrow[r], tmax[r]);
        float fsc = exp2f(mrow[r] - mn);
        mrow[r] = mn;
        lsum[r] *= fsc;
#pragma unroll
        for (int ni = 0; ni < 4; ++ni) oacc[ni][r] *= fsc;
      }
    }
    float psum[4] = {0.f, 0.f, 0.f, 0.f};
#pragma unroll
    for (int ni = 0; ni < 4; ++ni)
#pragma unroll
      for (int r = 0; r < 4; ++r) {
        float pv = exp2f(pm[ni][r] - mrow[r]);   // masked -> 0
        pm[ni][r] = pv;
        psum[r] += pv;
      }
#pragma unroll
    for (int r = 0; r < 4; ++r) {
#pragma unroll
      for (int o = 1; o < 16; o <<= 1) psum[r] += __shfl_xor(psum[r], o);
      lsum[r] += psum[r];
    }

    // P write: wave-private region, same-wave ds_write->ds_read, no barrier needed
#pragma unroll
    for (int ni = 0; ni < 4; ++ni)
#pragma unroll
      for (int r = 0; r < 4; ++r)
        Ps[(lg * 4 + r) * LDP + ni * 16 + lo] = f2bits(pm[ni][r]);

    // O += P @ V
#pragma unroll
    for (int kk = 0; kk < 2; ++kk) {
      bf16x8 pf = *(const bf16x8*)(&Ps[lo * LDP + kk * 32 + lg * 8]);
#pragma unroll
      for (int ni = 0; ni < 4; ++ni) {
        bf16x8 vf = *(const bf16x8*)(&Vs[(ni * 16 + lo) * LDP + kk * 32 + lg * 8]);
        oacc[ni] = __builtin_amdgcn_mfma_f32_16x16x32_bf16(pf, vf, oacc[ni], 0, 0, 0);
      }
    }
  }

#pragma unroll
  for (int r = 0; r < 4; ++r) {
    int tq = qb * 128 + w * 16 + lg * 4 + r;
    if (tq >= T) continue;
    float inv = 1.0f / lsum[r];
#pragma unroll
    for (int ni = 0; ni < 4; ++ni) {
      float o = oacc[ni][r] * inv;
      Y[((long)b * T + tq) * 1024 + h * 64 + ni * 16 + lo] = f2bits(o);
    }
  }
}

extern "C" void kernel_launch(void* const* d_in, const int* in_sizes, int n_in,
                              void* d_out, int out_size, void* d_ws, size_t ws_size,
                              hipStream_t stream) {
  const float* x   = (const float*)d_in[0];
  // d_in[1] = attn_mask (causal; applied analytically)
  const float* Wq  = (const float*)d_in[2];
  const float* Wk  = (const float*)d_in[3];
  const float* Wv  = (const float*)d_in[4];
  const float* Wo  = (const float*)d_in[5];
  const float* qg  = (const float*)d_in[6];
  const float* qb2 = (const float*)d_in[7];
  const float* kg  = (const float*)d_in[8];
  const float* kb2 = (const float*)d_in[9];

  const int B = 16, T = 582, C = 1024;
  const int M = B * T;          // 9312
  const int TPAD = 584;

  short* ws = (short*)d_ws;
  const long E  = (long)M * C;            // 9,535,488
  const long EV = (long)B * 16 * 64 * TPAD;
  short* xb   = ws;                       // bf16 x
  short* qpre = ws + E;
  short* kpre = ws + 2 * E;
  short* ka   = ws + 3 * E;
  short* vat  = ws + 4 * E;               // (B,H,D,TPAD)
  short* wb   = ws + 4 * E + EV + 1024;   // bf16 weights Wq|Wk|Wv|Wo (+pad for attn overreads)
  short* qa   = xb;                       // alias: xb dead after qkv-gemm
  short* y    = qpre;                     // alias: qpre dead after ln_rope
  float* out  = (float*)d_out;
  (void)ws_size; (void)in_sizes; (void)n_in; (void)out_size;

  const long WE = 1L << 20;               // elements per weight matrix

  cvt_x_kernel<<<(int)(E / 4 / 256), 256, 0, stream>>>(x, xb, E);
  cvt_w_kernel<<<(int)(4 * WE / 4 / 256), 256, 0, stream>>>(Wq, Wk, Wv, Wo, wb);

  // fused QKV projection: Bm = Wq|Wk|Wv as one [3072][1024] NT operand
  dim3 gqkv((M + 127) / 128, 3072 / 128);
  gemm_nt<3><<<gqkv, 256, 0, stream>>>(xb, wb, nullptr, qpre, kpre, vat, M, C, 3072, T, TPAD);
  ln_rope_kernel<<<dim3(M, 2), 256, 0, stream>>>(qpre, kpre, qg, qb2, kg, kb2, qa, ka, T);
  attn_kernel<<<dim3((T + 127) / 128, B * 16), 512, 0, stream>>>(qa, ka, vat, y, T, TPAD);
  dim3 gout((M + 127) / 128, C / 128);
  gemm_nt<2><<<gout, 256, 0, stream>>>(y, wb + 3 * WE, out, nullptr, nullptr, nullptr, M, C, C, T, TPAD);
}

// Round 17
// 237.287 us; speedup vs baseline: 1.0860x; 1.0860x over previous
//
#include <hip/hip_runtime.h>
#include <hip/hip_bf16.h>

typedef short bf16x8 __attribute__((ext_vector_type(8)));
typedef short bf16x4 __attribute__((ext_vector_type(4)));
typedef float f32x4  __attribute__((ext_vector_type(4)));

#define LDP 72   // padded LDS row (bf16 elems) for attn tiles

__device__ __forceinline__ float bits2f(short u) {
  return __uint_as_float(((unsigned int)(unsigned short)u) << 16);
}
__device__ __forceinline__ short f2bits(float f) {
  __hip_bfloat16 h = __float2bfloat16(f);
  return *reinterpret_cast<short*>(&h);
}
// async global->LDS, 16B per lane; LDS dest = wave-uniform base + lane*16
__device__ __forceinline__ void gld16(const short* g, short* l) {
  __builtin_amdgcn_global_load_lds(
      (const __attribute__((address_space(1))) void*)g,
      (__attribute__((address_space(3))) void*)l, 16, 0, 0);
}

// ---------------- fp32 -> bf16 casts (separate kernels, r7-verified) ----------------
__global__ __launch_bounds__(256)
void cvt_x_kernel(const float* __restrict__ src, short* __restrict__ dst, long n) {
  long i = ((long)blockIdx.x * 256 + threadIdx.x) * 4;
  if (i + 3 < n) {
    float4 v = *(const float4*)(src + i);
    bf16x4 o;
    o[0] = f2bits(v.x); o[1] = f2bits(v.y); o[2] = f2bits(v.z); o[3] = f2bits(v.w);
    *(bf16x4*)(dst + i) = o;
  }
}

__global__ __launch_bounds__(256)
void cvt_w_kernel(const float* __restrict__ w0, const float* __restrict__ w1,
                  const float* __restrict__ w2, const float* __restrict__ w3,
                  short* __restrict__ dst) {
  long i = ((long)blockIdx.x * 256 + threadIdx.x) * 4;
  int sel = (int)(i >> 20);
  const float* s = (sel == 0) ? w0 : (sel == 1) ? w1 : (sel == 2) ? w2 : w3;
  long off = i & ((1L << 20) - 1);
  float4 v = *(const float4*)(s + off);
  bf16x4 o;
  o[0] = f2bits(v.x); o[1] = f2bits(v.y); o[2] = f2bits(v.z); o[3] = f2bits(v.w);
  *(bf16x4*)(dst + i) = o;
}

// ---------------- GEMM (NT): Out = A[M][K] @ Bm[N][K]^T ----------------
// r6-verified: m97 2-phase, BK=64, XOR-swizzled LDS (0 bank conflicts), ~111us QKV.
// MODE 2: fp32 row-major [M][N] -> OutF
// MODE 3: fused QKV epilogue (N=3072): n<1024 -> Oq; n<2048 -> Ok; else V-transpose -> Ov
template<int MODE>
__global__ __launch_bounds__(256)
void gemm_nt(const short* __restrict__ A, const short* __restrict__ Bm,
             float* __restrict__ OutF, short* __restrict__ Oq,
             short* __restrict__ Ok, short* __restrict__ Ov,
             int M, int K, int N, int T, int TPAD) {
  __shared__ short As[128 * 64];
  __shared__ short Bs[128 * 64];
  const int tid = threadIdx.x;
  const int w = tid >> 6, l = tid & 63;
  const int wr = w >> 1, wc = w & 1;
  const int lg = l >> 4, lo = l & 15;
  const long row0 = (long)blockIdx.x * 128;
  const long col0 = (long)blockIdx.y * 128;

  const short* pa[4]; const short* pb[4]; short* la[4]; short* lb[4];
#pragma unroll
  for (int j = 0; j < 4; ++j) {
    const int ch = w * 4 + j;
    const int off = ch * 1024 + l * 16;             // byte offset in tile (lane's dest)
    const int row = off >> 7;                       // 128 B per row
    const int lc  = (off & 127) ^ ((row & 7) << 4); // inverse-swizzled source col (bytes)
    long ga = row0 + row; if (ga > M - 1) ga = M - 1;
    pa[j] = &A[ga * K + (lc >> 1)];
    pb[j] = &Bm[(col0 + row) * K + (lc >> 1)];
    la[j] = &As[ch * 512];                          // wave-uniform LDS base
    lb[j] = &Bs[ch * 512];
  }

  f32x4 acc[4][4] = {};

  for (int kt = 0; kt < K; kt += 64) {
    __syncthreads();
#pragma unroll
    for (int j = 0; j < 4; ++j) {
      gld16(pa[j] + kt, la[j]);
      gld16(pb[j] + kt, lb[j]);
    }
    __syncthreads();                       // compiler drains vmcnt before s_barrier
    bf16x8 af[4][2], bfr[4][2];
#pragma unroll
    for (int mi = 0; mi < 4; ++mi)
#pragma unroll
      for (int ks = 0; ks < 2; ++ks) {
        int pe = (ks * 32 + lg * 8) ^ ((lo & 7) << 3);   // swizzled read (elems)
        af[mi][ks] = *(const bf16x8*)(&As[(wr * 64 + mi * 16 + lo) * 64 + pe]);
      }
#pragma unroll
    for (int ni = 0; ni < 4; ++ni)
#pragma unroll
      for (int ks = 0; ks < 2; ++ks) {
        int pe = (ks * 32 + lg * 8) ^ ((lo & 7) << 3);
        bfr[ni][ks] = *(const bf16x8*)(&Bs[(wc * 64 + ni * 16 + lo) * 64 + pe]);
      }
#pragma unroll
    for (int mi = 0; mi < 4; ++mi)
#pragma unroll
      for (int ni = 0; ni < 4; ++ni)
#pragma unroll
        for (int ks = 0; ks < 2; ++ks)
          acc[mi][ni] = __builtin_amdgcn_mfma_f32_16x16x32_bf16(af[mi][ks], bfr[ni][ks], acc[mi][ni], 0, 0, 0);
  }

#pragma unroll
  for (int mi = 0; mi < 4; ++mi) {
#pragma unroll
    for (int r = 0; r < 4; ++r) {
      long m = row0 + wr * 64 + mi * 16 + lg * 4 + r;
      if (m >= M) continue;
#pragma unroll
      for (int ni = 0; ni < 4; ++ni) {
        long n = col0 + wc * 64 + ni * 16 + lo;
        float v = acc[mi][ni][r];
        if constexpr (MODE == 2) {
          OutF[m * (long)N + n] = v;
        } else {
          if (n < 1024) {
            Oq[m * 1024 + n] = f2bits(v);
          } else if (n < 2048) {
            Ok[m * 1024 + (n - 1024)] = f2bits(v);
          } else {
            long b = m / T, t = m - b * T;
            long nn = n - 2048, h = nn >> 6, dd = nn & 63;
            Ov[((b * 16 + h) * 64 + dd) * TPAD + t] = f2bits(v);
          }
        }
      }
    }
  }
}

// ---------------- LayerNorm(C=1024) + axial RoPE, write (B,H,T,D) bf16 ----------------
__global__ __launch_bounds__(256)
void ln_rope_kernel(const short* __restrict__ qpre, const short* __restrict__ kpre,
                    const float* __restrict__ qg, const float* __restrict__ qb2,
                    const float* __restrict__ kg, const float* __restrict__ kb2,
                    short* __restrict__ qa, short* __restrict__ ka, int T) {
  const int row = blockIdx.x;
  const short* in; const float *g, *be; short* out;
  if (blockIdx.y == 0) { in = qpre; g = qg; be = qb2; out = qa; }
  else                 { in = kpre; g = kg; be = kb2; out = ka; }
  const int tid = threadIdx.x;
  const int c0 = tid * 4;

  bf16x4 xv = *(const bf16x4*)(&in[(long)row * 1024 + c0]);
  float xf[4];
  float s = 0.f, sq = 0.f;
#pragma unroll
  for (int i = 0; i < 4; ++i) { xf[i] = bits2f(xv[i]); s += xf[i]; sq += xf[i] * xf[i]; }
#pragma unroll
  for (int o = 1; o < 64; o <<= 1) { s += __shfl_xor(s, o); sq += __shfl_xor(sq, o); }
  __shared__ float red[8];
  const int w = tid >> 6, l = tid & 63;
  if (l == 0) { red[w] = s; red[4 + w] = sq; }
  __syncthreads();
  s  = red[0] + red[1] + red[2] + red[3];
  sq = red[4] + red[5] + red[6] + red[7];
  const float mean = s * (1.0f / 1024.0f);
  const float var  = sq * (1.0f / 1024.0f) - mean * mean;
  const float rstd = rsqrtf(var + 1e-5f);

  float4 gv = *(const float4*)(&g[c0]);
  float4 bv = *(const float4*)(&be[c0]);
  float z[4];
  z[0] = (xf[0] - mean) * rstd * gv.x + bv.x;
  z[1] = (xf[1] - mean) * rstd * gv.y + bv.y;
  z[2] = (xf[2] - mean) * rstd * gv.z + bv.z;
  z[3] = (xf[3] - mean) * rstd * gv.w + bv.w;

  const int t = row % T;
  const int p = t - 6;                 // prefix = POSE + YAW = 6
  if (p >= 0) {
    const float tx = (float)(p % 18);  // END_X = 18
    const float ty = (float)(p / 18);
    const int jbase = (c0 & 63) >> 1;  // pair index 0..31
#pragma unroll
    for (int q2 = 0; q2 < 2; ++q2) {
      const int jj = jbase + q2;
      const int i  = jj & 15;
      const float freq = exp2f(-(float)i * 0.6228615177913804f); // log2(1000)/16
      const float ang  = ((jj < 16) ? tx : ty) * freq;
      float sv, cv;
      sincosf(ang, &sv, &cv);
      const float xe = z[q2 * 2], xo = z[q2 * 2 + 1];
      z[q2 * 2]     = xe * cv - xo * sv;
      z[q2 * 2 + 1] = xe * sv + xo * cv;
    }
  }
  const long b = row / T;
  const int h = c0 >> 6, d = c0 & 63;
  bf16x4 ov;
#pragma unroll
  for (int i = 0; i < 4; ++i) ov[i] = f2bits(z[i]);
  *(bf16x4*)(&out[(((b * 16 + h) * T) + t) * 64 + d]) = ov;
}

// ---------------- causal flash attention: QBLK=128, 8 waves, XCD-colocated grid ------------
// r16 structure (LDS-staged K/V, reg-prefetch, 2 barriers/tile, defer-max, mask hoist)
// with the grid axes SWAPPED: blockIdx.x = bh (256 = 8*32 -> flat%8 = bh%8, so ALL
// q-blocks of one (b,h) land on the SAME XCD and share K/V through that XCD's L2),
// blockIdx.y = q-block (reversed so heavy causal blocks dispatch first).
__global__ __launch_bounds__(512)
void attn_kernel(const short* __restrict__ Q, const short* __restrict__ Kk,
                 const short* __restrict__ Vt, short* __restrict__ Y,
                 int T, int TPAD) {
  __shared__ short QP[128 * LDP];         // Qs (prologue) aliased with 8 wave-private Ps
  __shared__ short Ks[64 * LDP];
  __shared__ short Vs[64 * LDP];          // Vs[d][key]
  const int tid = threadIdx.x;
  const int w = tid >> 6, l = tid & 63, lg = l >> 4, lo = l & 15;
  const int qb = gridDim.y - 1 - blockIdx.y;   // heavy causal blocks first
  const int bh = blockIdx.x;                   // bh on x: same-bh blocks -> same XCD
  const int b = bh >> 4, h = bh & 15;
  const long qbase = (long)bh * T * 64;
  short* Qs = QP;
  short* Ps = QP + w * 16 * LDP;          // wave-private P tile (8 x 16 rows = 128 = QP)

  const int r0 = tid >> 3, c0s = (tid & 7) * 8;   // 512 threads: one 16B chunk each

  // Q stage: 128 rows x 64 cols = 1024 chunks, 2 per thread
#pragma unroll
  for (int j = 0; j < 2; ++j) {
    int ch = tid + j * 512;
    int r = ch >> 3, c = (ch & 7) * 8;
    int t = qb * 128 + r; if (t > T - 1) t = T - 1;
    *(bf16x8*)(&Qs[r * LDP + c]) = *(const bf16x8*)(&Q[qbase + (long)t * 64 + c]);
  }
  __syncthreads();
  bf16x8 qf[2];
  qf[0] = *(const bf16x8*)(&Qs[(w * 16 + lo) * LDP + lg * 8]);
  qf[1] = *(const bf16x8*)(&Qs[(w * 16 + lo) * LDP + 32 + lg * 8]);

  float mrow[4], lsum[4];
  f32x4 oacc[4] = {};
#pragma unroll
  for (int r = 0; r < 4; ++r) { mrow[r] = -3e38f; lsum[r] = 0.f; }
  const float SCL = 0.125f * 1.44269504f;
  const int nkt = 2 * qb + 2;
  const int myTop = qb * 128 + w * 16 + 15;    // last q-row this wave owns

  bf16x8 kreg, vreg;
  const long vbase = (long)bh * 64;
  auto LOADKV = [&](int kt) {
    kreg = *(const bf16x8*)(&Kk[qbase + (long)(kt * 64 + r0) * 64 + c0s]);
    vreg = *(const bf16x8*)(&Vt[(vbase + r0) * TPAD + (long)kt * 64 + c0s]);
  };
  LOADKV(0);

  for (int kt = 0; kt < nkt; ++kt) {
    __syncthreads();                     // prev PV done reading Ks/Vs
    *(bf16x8*)(&Ks[r0 * LDP + c0s]) = kreg;
    *(bf16x8*)(&Vs[r0 * LDP + c0s]) = vreg;
    __syncthreads();                     // tile staged
    if (kt + 1 < nkt) LOADKV(kt + 1);    // reg prefetch hides HBM under softmax+MFMA

    if (kt * 64 > myTop) continue;       // wave fully masked for this tile (uniform)

    f32x4 sf[4] = {};
#pragma unroll
    for (int ni = 0; ni < 4; ++ni)
#pragma unroll
      for (int kk = 0; kk < 2; ++kk) {
        bf16x8 kfr = *(const bf16x8*)(&Ks[(ni * 16 + lo) * LDP + kk * 32 + lg * 8]);
        sf[ni] = __builtin_amdgcn_mfma_f32_16x16x32_bf16(qf[kk], kfr, sf[ni], 0, 0, 0);
      }

    float pm[4][4], tmax[4];
#pragma unroll
    for (int r = 0; r < 4; ++r) tmax[r] = -3e38f;
    if (kt >= 2 * qb) {                   // diagonal region: causal + T mask
#pragma unroll
      for (int ni = 0; ni < 4; ++ni)
#pragma unroll
        for (int r = 0; r < 4; ++r) {
          int key  = kt * 64 + ni * 16 + lo;
          int qrow = qb * 128 + w * 16 + lg * 4 + r;
          float sv = sf[ni][r] * SCL;
          if (key > qrow || key >= T) sv = -3e38f;
          pm[ni][r] = sv;
          tmax[r] = fmaxf(tmax[r], sv);
        }
    } else {                              // kt < 2*qb: provably unmasked
#pragma unroll
      for (int ni = 0; ni < 4; ++ni)
#pragma unroll
        for (int r = 0; r < 4; ++r) {
          float sv = sf[ni][r] * SCL;
          pm[ni][r] = sv;
          tmax[r] = fmaxf(tmax[r], sv);
        }
    }
#pragma unroll
    for (int r = 0; r < 4; ++r)
#pragma unroll
      for (int o = 1; o < 16; o <<= 1) tmax[r] = fmaxf(tmax[r], __shfl_xor(tmax[r], o));

    // T13 defer-max at THR=0 (exact): skip the rescale pass when no row max grew
    bool need = !__all(tmax[0] <= mrow[0] && tmax[1] <= mrow[1] &&
                       tmax[2] <= mrow[2] && tmax[3] <= mrow[3]);
    if (need) {
#pragma unroll
      for (int r = 0; r < 4; ++r) {
        float mn = fmaxf(mrow[r], tmax[r]);
        float fsc = exp2f(mrow[r] - mn);
        mrow[r] = mn;
        lsum[r] *= fsc;
#pragma unroll
        for (int ni = 0; ni < 4; ++ni) oacc[ni][r] *= fsc;
      }
    }
    float psum[4] = {0.f, 0.f, 0.f, 0.f};
#pragma unroll
    for (int ni = 0; ni < 4; ++ni)
#pragma unroll
      for (int r = 0; r < 4; ++r) {
        float pv = exp2f(pm[ni][r] - mrow[r]);   // masked -> 0
        pm[ni][r] = pv;
        psum[r] += pv;
      }
#pragma unroll
    for (int r = 0; r < 4; ++r) {
#pragma unroll
      for (int o = 1; o < 16; o <<= 1) psum[r] += __shfl_xor(psum[r], o);
      lsum[r] += psum[r];
    }

    // P write: wave-private region, same-wave ds_write->ds_read, no barrier needed
#pragma unroll
    for (int ni = 0; ni < 4; ++ni)
#pragma unroll
      for (int r = 0; r < 4; ++r)
        Ps[(lg * 4 + r) * LDP + ni * 16 + lo] = f2bits(pm[ni][r]);

    // O += P @ V
#pragma unroll
    for (int kk = 0; kk < 2; ++kk) {
      bf16x8 pf = *(const bf16x8*)(&Ps[lo * LDP + kk * 32 + lg * 8]);
#pragma unroll
      for (int ni = 0; ni < 4; ++ni) {
        bf16x8 vf = *(const bf16x8*)(&Vs[(ni * 16 + lo) * LDP + kk * 32 + lg * 8]);
        oacc[ni] = __builtin_amdgcn_mfma_f32_16x16x32_bf16(pf, vf, oacc[ni], 0, 0, 0);
      }
    }
  }

#pragma unroll
  for (int r = 0; r < 4; ++r) {
    int tq = qb * 128 + w * 16 + lg * 4 + r;
    if (tq >= T) continue;
    float inv = 1.0f / lsum[r];
#pragma unroll
    for (int ni = 0; ni < 4; ++ni) {
      float o = oacc[ni][r] * inv;
      Y[((long)b * T + tq) * 1024 + h * 64 + ni * 16 + lo] = f2bits(o);
    }
  }
}

extern "C" void kernel_launch(void* const* d_in, const int* in_sizes, int n_in,
                              void* d_out, int out_size, void* d_ws, size_t ws_size,
                              hipStream_t stream) {
  const float* x   = (const float*)d_in[0];
  // d_in[1] = attn_mask (causal; applied analytically)
  const float* Wq  = (const float*)d_in[2];
  const float* Wk  = (const float*)d_in[3];
  const float* Wv  = (const float*)d_in[4];
  const float* Wo  = (const float*)d_in[5];
  const float* qg  = (const float*)d_in[6];
  const float* qb2 = (const float*)d_in[7];
  const float* kg  = (const float*)d_in[8];
  const float* kb2 = (const float*)d_in[9];

  const int B = 16, T = 582, C = 1024;
  const int M = B * T;          // 9312
  const int TPAD = 584;

  short* ws = (short*)d_ws;
  const long E  = (long)M * C;            // 9,535,488
  const long EV = (long)B * 16 * 64 * TPAD;
  short* xb   = ws;                       // bf16 x
  short* qpre = ws + E;
  short* kpre = ws + 2 * E;
  short* ka   = ws + 3 * E;
  short* vat  = ws + 4 * E;               // (B,H,D,TPAD)
  short* wb   = ws + 4 * E + EV + 1024;   // bf16 weights Wq|Wk|Wv|Wo (+pad for attn overreads)
  short* qa   = xb;                       // alias: xb dead after qkv-gemm
  short* y    = qpre;                     // alias: qpre dead after ln_rope
  float* out  = (float*)d_out;
  (void)ws_size; (void)in_sizes; (void)n_in; (void)out_size;

  const long WE = 1L << 20;               // elements per weight matrix

  cvt_x_kernel<<<(int)(E / 4 / 256), 256, 0, stream>>>(x, xb, E);
  cvt_w_kernel<<<(int)(4 * WE / 4 / 256), 256, 0, stream>>>(Wq, Wk, Wv, Wo, wb);

  // fused QKV projection: Bm = Wq|Wk|Wv as one [3072][1024] NT operand
  dim3 gqkv((M + 127) / 128, 3072 / 128);
  gemm_nt<3><<<gqkv, 256, 0, stream>>>(xb, wb, nullptr, qpre, kpre, vat, M, C, 3072, T, TPAD);
  ln_rope_kernel<<<dim3(M, 2), 256, 0, stream>>>(qpre, kpre, qg, qb2, kg, kb2, qa, ka, T);
  attn_kernel<<<dim3(B * 16, (T + 127) / 128), 512, 0, stream>>>(qa, ka, vat, y, T, TPAD);
  dim3 gout((M + 127) / 128, C / 128);
  gemm_nt<2><<<gout, 256, 0, stream>>>(y, wb + 3 * WE, out, nullptr, nullptr, nullptr, M, C, C, T, TPAD);
}

// Round 18
// 236.028 us; speedup vs baseline: 1.0918x; 1.0053x over previous
//
#include <hip/hip_runtime.h>
#include <hip/hip_bf16.h>

typedef short bf16x8 __attribute__((ext_vector_type(8)));
typedef short bf16x4 __attribute__((ext_vector_type(4)));
typedef float f32x4  __attribute__((ext_vector_type(4)));

#define LDP 72   // padded LDS row (bf16 elems) for attn tiles

__device__ __forceinline__ float bits2f(short u) {
  return __uint_as_float(((unsigned int)(unsigned short)u) << 16);
}
__device__ __forceinline__ short f2bits(float f) {
  __hip_bfloat16 h = __float2bfloat16(f);
  return *reinterpret_cast<short*>(&h);
}
// async global->LDS, 16B per lane; LDS dest = wave-uniform base + lane*16
__device__ __forceinline__ void gld16(const short* g, short* l) {
  __builtin_amdgcn_global_load_lds(
      (const __attribute__((address_space(1))) void*)g,
      (__attribute__((address_space(3))) void*)l, 16, 0, 0);
}

// ---------------- fp32 -> bf16 casts (separate kernels, r7-verified) ----------------
__global__ __launch_bounds__(256)
void cvt_x_kernel(const float* __restrict__ src, short* __restrict__ dst, long n) {
  long i = ((long)blockIdx.x * 256 + threadIdx.x) * 4;
  if (i + 3 < n) {
    float4 v = *(const float4*)(src + i);
    bf16x4 o;
    o[0] = f2bits(v.x); o[1] = f2bits(v.y); o[2] = f2bits(v.z); o[3] = f2bits(v.w);
    *(bf16x4*)(dst + i) = o;
  }
}

__global__ __launch_bounds__(256)
void cvt_w_kernel(const float* __restrict__ w0, const float* __restrict__ w1,
                  const float* __restrict__ w2, const float* __restrict__ w3,
                  short* __restrict__ dst) {
  long i = ((long)blockIdx.x * 256 + threadIdx.x) * 4;
  int sel = (int)(i >> 20);
  const float* s = (sel == 0) ? w0 : (sel == 1) ? w1 : (sel == 2) ? w2 : w3;
  long off = i & ((1L << 20) - 1);
  float4 v = *(const float4*)(s + off);
  bf16x4 o;
  o[0] = f2bits(v.x); o[1] = f2bits(v.y); o[2] = f2bits(v.z); o[3] = f2bits(v.w);
  *(bf16x4*)(dst + i) = o;
}

// ---------------- GEMM (NT): Out = A[M][K] @ Bm[N][K]^T ----------------
// r6-verified: m97 2-phase, BK=64, XOR-swizzled LDS (0 bank conflicts), ~111us QKV.
// MODE 2: fp32 row-major [M][N] -> OutF
// MODE 3: fused QKV epilogue (N=3072): n<1024 -> Oq; n<2048 -> Ok; else V-transpose -> Ov
template<int MODE>
__global__ __launch_bounds__(256)
void gemm_nt(const short* __restrict__ A, const short* __restrict__ Bm,
             float* __restrict__ OutF, short* __restrict__ Oq,
             short* __restrict__ Ok, short* __restrict__ Ov,
             int M, int K, int N, int T, int TPAD) {
  __shared__ short As[128 * 64];
  __shared__ short Bs[128 * 64];
  const int tid = threadIdx.x;
  const int w = tid >> 6, l = tid & 63;
  const int wr = w >> 1, wc = w & 1;
  const int lg = l >> 4, lo = l & 15;
  const long row0 = (long)blockIdx.x * 128;
  const long col0 = (long)blockIdx.y * 128;

  const short* pa[4]; const short* pb[4]; short* la[4]; short* lb[4];
#pragma unroll
  for (int j = 0; j < 4; ++j) {
    const int ch = w * 4 + j;
    const int off = ch * 1024 + l * 16;             // byte offset in tile (lane's dest)
    const int row = off >> 7;                       // 128 B per row
    const int lc  = (off & 127) ^ ((row & 7) << 4); // inverse-swizzled source col (bytes)
    long ga = row0 + row; if (ga > M - 1) ga = M - 1;
    pa[j] = &A[ga * K + (lc >> 1)];
    pb[j] = &Bm[(col0 + row) * K + (lc >> 1)];
    la[j] = &As[ch * 512];                          // wave-uniform LDS base
    lb[j] = &Bs[ch * 512];
  }

  f32x4 acc[4][4] = {};

  for (int kt = 0; kt < K; kt += 64) {
    __syncthreads();
#pragma unroll
    for (int j = 0; j < 4; ++j) {
      gld16(pa[j] + kt, la[j]);
      gld16(pb[j] + kt, lb[j]);
    }
    __syncthreads();                       // compiler drains vmcnt before s_barrier
    bf16x8 af[4][2], bfr[4][2];
#pragma unroll
    for (int mi = 0; mi < 4; ++mi)
#pragma unroll
      for (int ks = 0; ks < 2; ++ks) {
        int pe = (ks * 32 + lg * 8) ^ ((lo & 7) << 3);   // swizzled read (elems)
        af[mi][ks] = *(const bf16x8*)(&As[(wr * 64 + mi * 16 + lo) * 64 + pe]);
      }
#pragma unroll
    for (int ni = 0; ni < 4; ++ni)
#pragma unroll
      for (int ks = 0; ks < 2; ++ks) {
        int pe = (ks * 32 + lg * 8) ^ ((lo & 7) << 3);
        bfr[ni][ks] = *(const bf16x8*)(&Bs[(wc * 64 + ni * 16 + lo) * 64 + pe]);
      }
#pragma unroll
    for (int mi = 0; mi < 4; ++mi)
#pragma unroll
      for (int ni = 0; ni < 4; ++ni)
#pragma unroll
        for (int ks = 0; ks < 2; ++ks)
          acc[mi][ni] = __builtin_amdgcn_mfma_f32_16x16x32_bf16(af[mi][ks], bfr[ni][ks], acc[mi][ni], 0, 0, 0);
  }

#pragma unroll
  for (int mi = 0; mi < 4; ++mi) {
#pragma unroll
    for (int r = 0; r < 4; ++r) {
      long m = row0 + wr * 64 + mi * 16 + lg * 4 + r;
      if (m >= M) continue;
#pragma unroll
      for (int ni = 0; ni < 4; ++ni) {
        long n = col0 + wc * 64 + ni * 16 + lo;
        float v = acc[mi][ni][r];
        if constexpr (MODE == 2) {
          OutF[m * (long)N + n] = v;
        } else {
          if (n < 1024) {
            Oq[m * 1024 + n] = f2bits(v);
          } else if (n < 2048) {
            Ok[m * 1024 + (n - 1024)] = f2bits(v);
          } else {
            long b = m / T, t = m - b * T;
            long nn = n - 2048, h = nn >> 6, dd = nn & 63;
            Ov[((b * 16 + h) * 64 + dd) * TPAD + t] = f2bits(v);
          }
        }
      }
    }
  }
}

// ---------------- LayerNorm(C=1024) + axial RoPE, write (B,H,T,D) bf16 ----------------
__global__ __launch_bounds__(256)
void ln_rope_kernel(const short* __restrict__ qpre, const short* __restrict__ kpre,
                    const float* __restrict__ qg, const float* __restrict__ qb2,
                    const float* __restrict__ kg, const float* __restrict__ kb2,
                    short* __restrict__ qa, short* __restrict__ ka, int T) {
  const int row = blockIdx.x;
  const short* in; const float *g, *be; short* out;
  if (blockIdx.y == 0) { in = qpre; g = qg; be = qb2; out = qa; }
  else                 { in = kpre; g = kg; be = kb2; out = ka; }
  const int tid = threadIdx.x;
  const int c0 = tid * 4;

  bf16x4 xv = *(const bf16x4*)(&in[(long)row * 1024 + c0]);
  float xf[4];
  float s = 0.f, sq = 0.f;
#pragma unroll
  for (int i = 0; i < 4; ++i) { xf[i] = bits2f(xv[i]); s += xf[i]; sq += xf[i] * xf[i]; }
#pragma unroll
  for (int o = 1; o < 64; o <<= 1) { s += __shfl_xor(s, o); sq += __shfl_xor(sq, o); }
  __shared__ float red[8];
  const int w = tid >> 6, l = tid & 63;
  if (l == 0) { red[w] = s; red[4 + w] = sq; }
  __syncthreads();
  s  = red[0] + red[1] + red[2] + red[3];
  sq = red[4] + red[5] + red[6] + red[7];
  const float mean = s * (1.0f / 1024.0f);
  const float var  = sq * (1.0f / 1024.0f) - mean * mean;
  const float rstd = rsqrtf(var + 1e-5f);

  float4 gv = *(const float4*)(&g[c0]);
  float4 bv = *(const float4*)(&be[c0]);
  float z[4];
  z[0] = (xf[0] - mean) * rstd * gv.x + bv.x;
  z[1] = (xf[1] - mean) * rstd * gv.y + bv.y;
  z[2] = (xf[2] - mean) * rstd * gv.z + bv.z;
  z[3] = (xf[3] - mean) * rstd * gv.w + bv.w;

  const int t = row % T;
  const int p = t - 6;                 // prefix = POSE + YAW = 6
  if (p >= 0) {
    const float tx = (float)(p % 18);  // END_X = 18
    const float ty = (float)(p / 18);
    const int jbase = (c0 & 63) >> 1;  // pair index 0..31
#pragma unroll
    for (int q2 = 0; q2 < 2; ++q2) {
      const int jj = jbase + q2;
      const int i  = jj & 15;
      const float freq = exp2f(-(float)i * 0.6228615177913804f); // log2(1000)/16
      const float ang  = ((jj < 16) ? tx : ty) * freq;
      float sv, cv;
      sincosf(ang, &sv, &cv);
      const float xe = z[q2 * 2], xo = z[q2 * 2 + 1];
      z[q2 * 2]     = xe * cv - xo * sv;
      z[q2 * 2 + 1] = xe * sv + xo * cv;
    }
  }
  const long b = row / T;
  const int h = c0 >> 6, d = c0 & 63;
  bf16x4 ov;
#pragma unroll
  for (int i = 0; i < 4; ++i) ov[i] = f2bits(z[i]);
  *(bf16x4*)(&out[(((b * 16 + h) * T) + t) * 64 + d]) = ov;
}

// ---------------- causal flash attention: QBLK=128, 8 waves, XCD-colocated grid ------------
// r17 session-best structure (LDS-staged K/V, reg-prefetch, 2 barriers/tile, mask
// hoist, bh-on-x grid so all q-blocks of one (b,h) share an XCD's L2).
// r18 additions: (1) T13 defer-max THR=8 (HK setting) — skip the O/lsum rescale
// unless a row max grew by >8 in log2 units; P then bounded by 2^8=256 (bf16-safe,
// f32 lsum safe; mathematically exact). (2) T5 setprio(1) around both MFMA clusters.
__global__ __launch_bounds__(512)
void attn_kernel(const short* __restrict__ Q, const short* __restrict__ Kk,
                 const short* __restrict__ Vt, short* __restrict__ Y,
                 int T, int TPAD) {
  __shared__ short QP[128 * LDP];         // Qs (prologue) aliased with 8 wave-private Ps
  __shared__ short Ks[64 * LDP];
  __shared__ short Vs[64 * LDP];          // Vs[d][key]
  const int tid = threadIdx.x;
  const int w = tid >> 6, l = tid & 63, lg = l >> 4, lo = l & 15;
  const int qb = gridDim.y - 1 - blockIdx.y;   // heavy causal blocks first
  const int bh = blockIdx.x;                   // bh on x: same-bh blocks -> same XCD
  const int b = bh >> 4, h = bh & 15;
  const long qbase = (long)bh * T * 64;
  short* Qs = QP;
  short* Ps = QP + w * 16 * LDP;          // wave-private P tile (8 x 16 rows = 128 = QP)

  const int r0 = tid >> 3, c0s = (tid & 7) * 8;   // 512 threads: one 16B chunk each

  // Q stage: 128 rows x 64 cols = 1024 chunks, 2 per thread
#pragma unroll
  for (int j = 0; j < 2; ++j) {
    int ch = tid + j * 512;
    int r = ch >> 3, c = (ch & 7) * 8;
    int t = qb * 128 + r; if (t > T - 1) t = T - 1;
    *(bf16x8*)(&Qs[r * LDP + c]) = *(const bf16x8*)(&Q[qbase + (long)t * 64 + c]);
  }
  __syncthreads();
  bf16x8 qf[2];
  qf[0] = *(const bf16x8*)(&Qs[(w * 16 + lo) * LDP + lg * 8]);
  qf[1] = *(const bf16x8*)(&Qs[(w * 16 + lo) * LDP + 32 + lg * 8]);

  float mrow[4], lsum[4];
  f32x4 oacc[4] = {};
#pragma unroll
  for (int r = 0; r < 4; ++r) { mrow[r] = -3e38f; lsum[r] = 0.f; }
  const float SCL = 0.125f * 1.44269504f;
  const float THR = 8.0f;                      // defer-max threshold (log2 units)
  const int nkt = 2 * qb + 2;
  const int myTop = qb * 128 + w * 16 + 15;    // last q-row this wave owns

  bf16x8 kreg, vreg;
  const long vbase = (long)bh * 64;
  auto LOADKV = [&](int kt) {
    kreg = *(const bf16x8*)(&Kk[qbase + (long)(kt * 64 + r0) * 64 + c0s]);
    vreg = *(const bf16x8*)(&Vt[(vbase + r0) * TPAD + (long)kt * 64 + c0s]);
  };
  LOADKV(0);

  for (int kt = 0; kt < nkt; ++kt) {
    __syncthreads();                     // prev PV done reading Ks/Vs
    *(bf16x8*)(&Ks[r0 * LDP + c0s]) = kreg;
    *(bf16x8*)(&Vs[r0 * LDP + c0s]) = vreg;
    __syncthreads();                     // tile staged
    if (kt + 1 < nkt) LOADKV(kt + 1);    // reg prefetch hides HBM under softmax+MFMA

    if (kt * 64 > myTop) continue;       // wave fully masked for this tile (uniform)

    f32x4 sf[4] = {};
    __builtin_amdgcn_s_setprio(1);
#pragma unroll
    for (int ni = 0; ni < 4; ++ni)
#pragma unroll
      for (int kk = 0; kk < 2; ++kk) {
        bf16x8 kfr = *(const bf16x8*)(&Ks[(ni * 16 + lo) * LDP + kk * 32 + lg * 8]);
        sf[ni] = __builtin_amdgcn_mfma_f32_16x16x32_bf16(qf[kk], kfr, sf[ni], 0, 0, 0);
      }
    __builtin_amdgcn_s_setprio(0);

    float pm[4][4], tmax[4];
#pragma unroll
    for (int r = 0; r < 4; ++r) tmax[r] = -3e38f;
    if (kt >= 2 * qb) {                   // diagonal region: causal + T mask
#pragma unroll
      for (int ni = 0; ni < 4; ++ni)
#pragma unroll
        for (int r = 0; r < 4; ++r) {
          int key  = kt * 64 + ni * 16 + lo;
          int qrow = qb * 128 + w * 16 + lg * 4 + r;
          float sv = sf[ni][r] * SCL;
          if (key > qrow || key >= T) sv = -3e38f;
          pm[ni][r] = sv;
          tmax[r] = fmaxf(tmax[r], sv);
        }
    } else {                              // kt < 2*qb: provably unmasked
#pragma unroll
      for (int ni = 0; ni < 4; ++ni)
#pragma unroll
        for (int r = 0; r < 4; ++r) {
          float sv = sf[ni][r] * SCL;
          pm[ni][r] = sv;
          tmax[r] = fmaxf(tmax[r], sv);
        }
    }
#pragma unroll
    for (int r = 0; r < 4; ++r)
#pragma unroll
      for (int o = 1; o < 16; o <<= 1) tmax[r] = fmaxf(tmax[r], __shfl_xor(tmax[r], o));

    // T13 defer-max THR=8: rescale only when a row max grows by > THR (P <= 2^8)
    bool need = !__all(tmax[0] <= mrow[0] + THR && tmax[1] <= mrow[1] + THR &&
                       tmax[2] <= mrow[2] + THR && tmax[3] <= mrow[3] + THR);
    if (need) {
#pragma unroll
      for (int r = 0; r < 4; ++r) {
        float mn = fmaxf(mrow[r], tmax[r]);
        float fsc = exp2f(mrow[r] - mn);
        mrow[r] = mn;
        lsum[r] *= fsc;
#pragma unroll
        for (int ni = 0; ni < 4; ++ni) oacc[ni][r] *= fsc;
      }
    }
    float psum[4] = {0.f, 0.f, 0.f, 0.f};
#pragma unroll
    for (int ni = 0; ni < 4; ++ni)
#pragma unroll
      for (int r = 0; r < 4; ++r) {
        float pv = exp2f(pm[ni][r] - mrow[r]);   // masked -> 0; bounded by 2^THR
        pm[ni][r] = pv;
        psum[r] += pv;
      }
#pragma unroll
    for (int r = 0; r < 4; ++r) {
#pragma unroll
      for (int o = 1; o < 16; o <<= 1) psum[r] += __shfl_xor(psum[r], o);
      lsum[r] += psum[r];
    }

    // P write: wave-private region, same-wave ds_write->ds_read, no barrier needed
#pragma unroll
    for (int ni = 0; ni < 4; ++ni)
#pragma unroll
      for (int r = 0; r < 4; ++r)
        Ps[(lg * 4 + r) * LDP + ni * 16 + lo] = f2bits(pm[ni][r]);

    // O += P @ V
    __builtin_amdgcn_s_setprio(1);
#pragma unroll
    for (int kk = 0; kk < 2; ++kk) {
      bf16x8 pf = *(const bf16x8*)(&Ps[lo * LDP + kk * 32 + lg * 8]);
#pragma unroll
      for (int ni = 0; ni < 4; ++ni) {
        bf16x8 vf = *(const bf16x8*)(&Vs[(ni * 16 + lo) * LDP + kk * 32 + lg * 8]);
        oacc[ni] = __builtin_amdgcn_mfma_f32_16x16x32_bf16(pf, vf, oacc[ni], 0, 0, 0);
      }
    }
    __builtin_amdgcn_s_setprio(0);
  }

#pragma unroll
  for (int r = 0; r < 4; ++r) {
    int tq = qb * 128 + w * 16 + lg * 4 + r;
    if (tq >= T) continue;
    float inv = 1.0f / lsum[r];
#pragma unroll
    for (int ni = 0; ni < 4; ++ni) {
      float o = oacc[ni][r] * inv;
      Y[((long)b * T + tq) * 1024 + h * 64 + ni * 16 + lo] = f2bits(o);
    }
  }
}

extern "C" void kernel_launch(void* const* d_in, const int* in_sizes, int n_in,
                              void* d_out, int out_size, void* d_ws, size_t ws_size,
                              hipStream_t stream) {
  const float* x   = (const float*)d_in[0];
  // d_in[1] = attn_mask (causal; applied analytically)
  const float* Wq  = (const float*)d_in[2];
  const float* Wk  = (const float*)d_in[3];
  const float* Wv  = (const float*)d_in[4];
  const float* Wo  = (const float*)d_in[5];
  const float* qg  = (const float*)d_in[6];
  const float* qb2 = (const float*)d_in[7];
  const float* kg  = (const float*)d_in[8];
  const float* kb2 = (const float*)d_in[9];

  const int B = 16, T = 582, C = 1024;
  const int M = B * T;          // 9312
  const int TPAD = 584;

  short* ws = (short*)d_ws;
  const long E  = (long)M * C;            // 9,535,488
  const long EV = (long)B * 16 * 64 * TPAD;
  short* xb   = ws;                       // bf16 x
  short* qpre = ws + E;
  short* kpre = ws + 2 * E;
  short* ka   = ws + 3 * E;
  short* vat  = ws + 4 * E;               // (B,H,D,TPAD)
  short* wb   = ws + 4 * E + EV + 1024;   // bf16 weights Wq|Wk|Wv|Wo (+pad for attn overreads)
  short* qa   = xb;                       // alias: xb dead after qkv-gemm
  short* y    = qpre;                     // alias: qpre dead after ln_rope
  float* out  = (float*)d_out;
  (void)ws_size; (void)in_sizes; (void)n_in; (void)out_size;

  const long WE = 1L << 20;               // elements per weight matrix

  cvt_x_kernel<<<(int)(E / 4 / 256), 256, 0, stream>>>(x, xb, E);
  cvt_w_kernel<<<(int)(4 * WE / 4 / 256), 256, 0, stream>>>(Wq, Wk, Wv, Wo, wb);

  // fused QKV projection: Bm = Wq|Wk|Wv as one [3072][1024] NT operand
  dim3 gqkv((M + 127) / 128, 3072 / 128);
  gemm_nt<3><<<gqkv, 256, 0, stream>>>(xb, wb, nullptr, qpre, kpre, vat, M, C, 3072, T, TPAD);
  ln_rope_kernel<<<dim3(M, 2), 256, 0, stream>>>(qpre, kpre, qg, qb2, kg, kb2, qa, ka, T);
  attn_kernel<<<dim3(B * 16, (T + 127) / 128), 512, 0, stream>>>(qa, ka, vat, y, T, TPAD);
  dim3 gout((M + 127) / 128, C / 128);
  gemm_nt<2><<<gout, 256, 0, stream>>>(y, wb + 3 * WE, out, nullptr, nullptr, nullptr, M, C, C, T, TPAD);
}